// Round 6
// baseline (173.336 us; speedup 1.0000x reference)
//
#include <hip/hip_runtime.h>
#include <stdint.h>

typedef __attribute__((ext_vector_type(8))) short short8;
typedef __attribute__((ext_vector_type(4))) float f32x4;

// ---------------- geometry ----------------
#define B_TOTAL     131072
#define WG_THREADS  512
#define WAVES       8
#define T_TILES     2                      // 16-row batch tiles per wave
#define ROWS_PER_WG (WAVES * T_TILES * 16) // 256
#define NUM_WG      (B_TOTAL / ROWS_PER_WG) // 512 -> 4 WG/CU at 35KB LDS

// ---------------- d_ws layout ----------------
// A1: W0^T frags  [mt4][kt4][64][8] bf16 = 16 KB @ short 0     (L1-resident)
// A2: W1^T frags  [mt4][kt2][64][8] bf16 =  8 KB @ short 8192  (L1-resident)
// A3: hw1^T frags [n32][kt2][64][8] bf16 = 64 KB @ short 12288 (L2-resident)
// w2v: per-lane w2 [n32][64]{4 f32}      = 32 KB @ byte 90112  (L2-resident)
#define A1_SH   0
#define A2_SH   8192
#define A3_SH   12288
#define W2V_OFF 90112

// LDS (all wave-private, zero barriers):
//   fw:   per-wave f buffer [16][72] shorts = 18.4 KB
//   obuf: per-wave out staging [16][33] f32 = 16.9 KB   => 35.3 KB -> 4 WG/CU
#define FSTRIDE 72
#define SMEM_SHORTS (WAVES * 16 * FSTRIDE)
#define OSTRIDE 33

__device__ __forceinline__ short f2bf(float x) {
  union { float f; uint32_t u; } v; v.f = x;
  uint32_t r = (v.u + 0x7FFFu + ((v.u >> 16) & 1u)) >> 16;
  return (short)r;
}

__device__ __forceinline__ uint32_t pack2(float a, float b) {
  return (uint32_t)(uint16_t)f2bf(a) | ((uint32_t)(uint16_t)f2bf(b) << 16);
}

// ---------------- weight prep: f32 -> bf16 MFMA A-fragment order ----------------
__global__ void prep_kernel(const float* __restrict__ W0, const float* __restrict__ W1,
                            const float* __restrict__ hw1, const float* __restrict__ hw2,
                            short* __restrict__ wsA, float* __restrict__ w2v) {
  int idx = blockIdx.x * 256 + threadIdx.x;
  int stride = gridDim.x * 256;
  // A1[m][k] = W0[k][m]  (m: hidden 64, k: input 128)
  for (int i = idx; i < 8192; i += stride) {
    int j = i & 7, l = (i >> 3) & 63, kt = (i >> 9) & 3, mt = i >> 11;
    int m = mt * 16 + (l & 15), k = kt * 32 + (l >> 4) * 8 + j;
    wsA[A1_SH + i] = f2bf(W0[k * 64 + m]);
  }
  // A2[m][k] = W1[k][m]
  for (int i = idx; i < 4096; i += stride) {
    int j = i & 7, l = (i >> 3) & 63, kt = (i >> 9) & 1, mt = i >> 10;
    int m = mt * 16 + (l & 15), k = kt * 32 + (l >> 4) * 8 + j;
    wsA[A2_SH + i] = f2bf(W1[k * 64 + m]);
  }
  // A3[n*16+d][k] = hw1[n][k][d]
  for (int i = idx; i < 32768; i += stride) {
    int j = i & 7, l = (i >> 3) & 63, kt = (i >> 9) & 1, n = i >> 10;
    int d = l & 15, k = kt * 32 + (l >> 4) * 8 + j;
    wsA[A3_SH + i] = f2bf(hw1[(n * 64 + k) * 16 + d]);
  }
  // w2v[n][lane][i] = hw2[n][(lane>>4)*4 + i]
  for (int i = idx; i < 8192; i += stride) {
    int ii = i & 3, l = (i >> 2) & 63, n = i >> 8;
    w2v[i] = hw2[n * 16 + (l >> 4) * 4 + ii];
  }
}

// ---------------- fused main kernel ----------------
__global__ __launch_bounds__(WG_THREADS, 8)   // 8 waves/EU: VGPR cap 64
void mhc_kernel(const float* __restrict__ x, const float* __restrict__ b0,
                const float* __restrict__ b1, const float* __restrict__ hb1,
                const float* __restrict__ hb2, const short* __restrict__ wsA,
                const float* __restrict__ w2v, float* __restrict__ out) {
  __shared__ short smem[SMEM_SHORTS];
  __shared__ float obuf[WAVES * 16 * OSTRIDE];

  const int tid = threadIdx.x;
  const int w = tid >> 6, l = tid & 63;
  const int g = l >> 4, c = l & 15;
  const int rowbase = blockIdx.x * ROWS_PER_WG + w * (T_TILES * 16);

  short* fw = smem + w * (16 * FSTRIDE); // wave-private f-tile
  float* ow = obuf + w * (16 * OSTRIDE); // wave-private out staging

  for (int t = 0; t < T_TILES; ++t) {
    // ---- x fragment loads (f32, 2x dwordx4 per K-tile) ----
    const float* xp = x + (size_t)(rowbase + t * 16 + c) * 128 + g * 8;
    float4 xr[4][2];
#pragma unroll
    for (int kt = 0; kt < 4; ++kt) {
      xr[kt][0] = *(const float4*)(xp + kt * 32);
      xr[kt][1] = *(const float4*)(xp + kt * 32 + 4);
    }
    short8 bx[4];
#pragma unroll
    for (int kt = 0; kt < 4; ++kt) {
      float4 a = xr[kt][0], bq = xr[kt][1];
      short8 v;
      v[0] = f2bf(a.x);  v[1] = f2bf(a.y);  v[2] = f2bf(a.z);  v[3] = f2bf(a.w);
      v[4] = f2bf(bq.x); v[5] = f2bf(bq.y); v[6] = f2bf(bq.z); v[7] = f2bf(bq.w);
      bx[kt] = v;
    }
    // ---- GEMM1: f0^T = W0^T x^T  (M=64, K=128); A1 frags from L1 ----
#pragma unroll
    for (int mt = 0; mt < 4; ++mt) {
      f32x4 acc = {0.f, 0.f, 0.f, 0.f};
#pragma unroll
      for (int kt = 0; kt < 4; ++kt)
        acc = __builtin_amdgcn_mfma_f32_16x16x32_bf16(
            *(const short8*)(wsA + A1_SH + ((mt * 4 + kt) * 64 + l) * 8),
            bx[kt], acc, 0, 0, 0);
      float4 bv = *(const float4*)(b0 + mt * 16 + g * 4);  // L1 hit
      uint2 pp;
      pp.x = pack2(fmaxf(acc[0] + bv.x, 0.f), fmaxf(acc[1] + bv.y, 0.f));
      pp.y = pack2(fmaxf(acc[2] + bv.z, 0.f), fmaxf(acc[3] + bv.w, 0.f));
      *(uint2*)(fw + c * FSTRIDE + mt * 16 + g * 4) = pp;   // f0[c][m], contiguous
    }
    // f0 B-fragments (wave-private LDS round trip, no barrier needed)
    short8 b2_0 = *(const short8*)(fw + c * FSTRIDE + g * 8);
    short8 b2_1 = *(const short8*)(fw + c * FSTRIDE + 32 + g * 8);
    // ---- GEMM2: f1^T = W1^T f0^T  (M=64, K=64); A2 frags from L1 ----
#pragma unroll
    for (int mt = 0; mt < 4; ++mt) {
      f32x4 acc = {0.f, 0.f, 0.f, 0.f};
      acc = __builtin_amdgcn_mfma_f32_16x16x32_bf16(
          *(const short8*)(wsA + A2_SH + ((mt * 2 + 0) * 64 + l) * 8), b2_0, acc, 0, 0, 0);
      acc = __builtin_amdgcn_mfma_f32_16x16x32_bf16(
          *(const short8*)(wsA + A2_SH + ((mt * 2 + 1) * 64 + l) * 8), b2_1, acc, 0, 0, 0);
      float4 bv = *(const float4*)(b1 + mt * 16 + g * 4);  // L1 hit
      uint2 pp;
      pp.x = pack2(fmaxf(acc[0] + bv.x, 0.f), fmaxf(acc[1] + bv.y, 0.f));
      pp.y = pack2(fmaxf(acc[2] + bv.z, 0.f), fmaxf(acc[3] + bv.w, 0.f));
      *(uint2*)(fw + c * FSTRIDE + mt * 16 + g * 4) = pp;   // f1 overwrites f0
    }
    short8 b3_0 = *(const short8*)(fw + c * FSTRIDE + g * 8);
    short8 b3_1 = *(const short8*)(fw + c * FSTRIDE + 32 + g * 8);

    // ---- heads: runtime n-loop; A3/w2v from L2 (wave reads 1KB contiguous);
    //      output staged in wave-private LDS then stored as full 64B lines ----
#pragma unroll 2
    for (int n = 0; n < 32; ++n) {
      short8 a30 = *(const short8*)(wsA + A3_SH + ((n * 2 + 0) * 64 + l) * 8);
      short8 a31 = *(const short8*)(wsA + A3_SH + ((n * 2 + 1) * 64 + l) * 8);
      float4 wl  = *(const float4*)(w2v + n * 256 + l * 4);
      float4 hbv = *(const float4*)(hb1 + n * 16 + g * 4);
      f32x4 acc = {0.f, 0.f, 0.f, 0.f};
      acc = __builtin_amdgcn_mfma_f32_16x16x32_bf16(a30, b3_0, acc, 0, 0, 0);
      acc = __builtin_amdgcn_mfma_f32_16x16x32_bf16(a31, b3_1, acc, 0, 0, 0);
      float s = fmaxf(acc[0] + hbv.x, 0.f) * wl.x
              + fmaxf(acc[1] + hbv.y, 0.f) * wl.y
              + fmaxf(acc[2] + hbv.z, 0.f) * wl.z
              + fmaxf(acc[3] + hbv.w, 0.f) * wl.w;
      s += __shfl_xor(s, 16);
      s += __shfl_xor(s, 32);
      s += hb2[n];
      if (g == (n >> 3)) ow[c * OSTRIDE + n] = s;  // conflict-free (stride 33)
    }
    // wave-private readback (<=2-way bank alias = free) + full-line stores
    float r[8];
#pragma unroll
    for (int j = 0; j < 8; ++j) r[j] = ow[c * OSTRIDE + g * 8 + j];
    float4 v0 = {r[0], r[1], r[2], r[3]};
    float4 v1 = {r[4], r[5], r[6], r[7]};
    float* op = out + (size_t)(rowbase + t * 16 + c) * 32 + g * 8;
    *(float4*)op = v0;
    *(float4*)(op + 4) = v1;
  }
}

extern "C" void kernel_launch(void* const* d_in, const int* in_sizes, int n_in,
                              void* d_out, int out_size, void* d_ws, size_t ws_size,
                              hipStream_t stream) {
  const float* x   = (const float*)d_in[0];
  const float* W0  = (const float*)d_in[1];
  const float* b0  = (const float*)d_in[2];
  const float* W1  = (const float*)d_in[3];
  const float* b1  = (const float*)d_in[4];
  const float* hw1 = (const float*)d_in[5];
  const float* hb1 = (const float*)d_in[6];
  const float* hw2 = (const float*)d_in[7];
  const float* hb2 = (const float*)d_in[8];
  float* out = (float*)d_out;

  short* wsA = (short*)d_ws;
  float* w2v = (float*)((char*)d_ws + W2V_OFF);

  prep_kernel<<<128, 256, 0, stream>>>(W0, W1, hw1, hw2, wsA, w2v);
  mhc_kernel<<<NUM_WG, WG_THREADS, 0, stream>>>(x, b0, b1, hb1, hb2, wsA, w2v, out);
}

// Round 10
// 159.418 us; speedup vs baseline: 1.0873x; 1.0873x over previous
//
#include <hip/hip_runtime.h>
#include <stdint.h>

typedef __attribute__((ext_vector_type(8))) short short8;
typedef __attribute__((ext_vector_type(4))) float f32x4;

// ---------------- geometry ----------------
#define B_TOTAL     131072
#define WG_THREADS  512
#define WAVES       8
#define T_TILES     1                      // 16-row batch tiles per wave
#define ROWS_PER_WG (WAVES * T_TILES * 16) // 128
#define NUM_WG      (B_TOTAL / ROWS_PER_WG) // 1024 -> 4 WG/CU (grid, LDS both allow)

// ---------------- d_ws layout ----------------
// A1: W0^T frags  [mt4][kt4][64][8] bf16 = 16 KB @ short 0     (L1-resident)
// A2: W1^T frags  [mt4][kt2][64][8] bf16 =  8 KB @ short 8192  (L1-resident)
// A3: hw1^T frags [n32][kt2][64][8] bf16 = 64 KB @ short 12288 (L2-resident)
// w2v: per-lane w2 [n32][64]{4 f32}      = 32 KB @ byte 90112  (L2-resident)
#define A1_SH   0
#define A2_SH   8192
#define A3_SH   12288
#define W2V_OFF 90112

// LDS (all wave-private, zero barriers):
//   fw:   per-wave f buffer [16][72] shorts = 18.4 KB
//   obuf: per-wave out staging [16][33] f32 = 16.9 KB   => 35.3 KB -> 4 WG/CU
#define FSTRIDE 72
#define SMEM_SHORTS (WAVES * 16 * FSTRIDE)
#define OSTRIDE 33

__device__ __forceinline__ short f2bf(float x) {
  union { float f; uint32_t u; } v; v.f = x;
  uint32_t r = (v.u + 0x7FFFu + ((v.u >> 16) & 1u)) >> 16;
  return (short)r;
}

__device__ __forceinline__ uint32_t pack2(float a, float b) {
  return (uint32_t)(uint16_t)f2bf(a) | ((uint32_t)(uint16_t)f2bf(b) << 16);
}

// ---------------- weight prep: f32 -> bf16 MFMA A-fragment order ----------------
__global__ void prep_kernel(const float* __restrict__ W0, const float* __restrict__ W1,
                            const float* __restrict__ hw1, const float* __restrict__ hw2,
                            short* __restrict__ wsA, float* __restrict__ w2v) {
  int idx = blockIdx.x * 256 + threadIdx.x;
  int stride = gridDim.x * 256;
  // A1[m][k] = W0[k][m]  (m: hidden 64, k: input 128)
  for (int i = idx; i < 8192; i += stride) {
    int j = i & 7, l = (i >> 3) & 63, kt = (i >> 9) & 3, mt = i >> 11;
    int m = mt * 16 + (l & 15), k = kt * 32 + (l >> 4) * 8 + j;
    wsA[A1_SH + i] = f2bf(W0[k * 64 + m]);
  }
  // A2[m][k] = W1[k][m]
  for (int i = idx; i < 4096; i += stride) {
    int j = i & 7, l = (i >> 3) & 63, kt = (i >> 9) & 1, mt = i >> 10;
    int m = mt * 16 + (l & 15), k = kt * 32 + (l >> 4) * 8 + j;
    wsA[A2_SH + i] = f2bf(W1[k * 64 + m]);
  }
  // A3[n*16+d][k] = hw1[n][k][d]
  for (int i = idx; i < 32768; i += stride) {
    int j = i & 7, l = (i >> 3) & 63, kt = (i >> 9) & 1, n = i >> 10;
    int d = l & 15, k = kt * 32 + (l >> 4) * 8 + j;
    wsA[A3_SH + i] = f2bf(hw1[(n * 64 + k) * 16 + d]);
  }
  // w2v[n][lane][i] = hw2[n][(lane>>4)*4 + i]
  for (int i = idx; i < 8192; i += stride) {
    int ii = i & 3, l = (i >> 2) & 63, n = i >> 8;
    w2v[i] = hw2[n * 16 + (l >> 4) * 4 + ii];
  }
}

// ---------------- fused main kernel ----------------
// (512,4): 128-VGPR cap — R4 compiled this code shape at 56 VGPR, no spills.
// Actual ~56-70 regs => HW allows 7-8 waves/SIMD; LDS 35.3KB + grid 1024 => 4 WG/CU.
__global__ __launch_bounds__(WG_THREADS, 4)
void mhc_kernel(const float* __restrict__ x, const float* __restrict__ b0,
                const float* __restrict__ b1, const float* __restrict__ hb1,
                const float* __restrict__ hb2, const short* __restrict__ wsA,
                const float* __restrict__ w2v, float* __restrict__ out) {
  __shared__ short smem[SMEM_SHORTS];
  __shared__ float obuf[WAVES * 16 * OSTRIDE];

  const int tid = threadIdx.x;
  const int w = tid >> 6, l = tid & 63;
  const int g = l >> 4, c = l & 15;
  const int rowbase = blockIdx.x * ROWS_PER_WG + w * (T_TILES * 16);

  short* fw = smem + w * (16 * FSTRIDE); // wave-private f-tile
  float* ow = obuf + w * (16 * OSTRIDE); // wave-private out staging

  for (int t = 0; t < T_TILES; ++t) {
    // ---- x fragment loads (f32, 2x dwordx4 per K-tile) ----
    const float* xp = x + (size_t)(rowbase + t * 16 + c) * 128 + g * 8;
    float4 xr[4][2];
#pragma unroll
    for (int kt = 0; kt < 4; ++kt) {
      xr[kt][0] = *(const float4*)(xp + kt * 32);
      xr[kt][1] = *(const float4*)(xp + kt * 32 + 4);
    }
    short8 bx[4];
#pragma unroll
    for (int kt = 0; kt < 4; ++kt) {
      float4 a = xr[kt][0], bq = xr[kt][1];
      short8 v;
      v[0] = f2bf(a.x);  v[1] = f2bf(a.y);  v[2] = f2bf(a.z);  v[3] = f2bf(a.w);
      v[4] = f2bf(bq.x); v[5] = f2bf(bq.y); v[6] = f2bf(bq.z); v[7] = f2bf(bq.w);
      bx[kt] = v;
    }
    // ---- GEMM1: f0^T = W0^T x^T  (M=64, K=128); A1 frags from L1 ----
#pragma unroll
    for (int mt = 0; mt < 4; ++mt) {
      f32x4 acc = {0.f, 0.f, 0.f, 0.f};
#pragma unroll
      for (int kt = 0; kt < 4; ++kt)
        acc = __builtin_amdgcn_mfma_f32_16x16x32_bf16(
            *(const short8*)(wsA + A1_SH + ((mt * 4 + kt) * 64 + l) * 8),
            bx[kt], acc, 0, 0, 0);
      float4 bv = *(const float4*)(b0 + mt * 16 + g * 4);  // L1 hit
      uint2 pp;
      pp.x = pack2(fmaxf(acc[0] + bv.x, 0.f), fmaxf(acc[1] + bv.y, 0.f));
      pp.y = pack2(fmaxf(acc[2] + bv.z, 0.f), fmaxf(acc[3] + bv.w, 0.f));
      *(uint2*)(fw + c * FSTRIDE + mt * 16 + g * 4) = pp;   // f0[c][m], contiguous
    }
    // f0 B-fragments (wave-private LDS round trip, no barrier needed)
    short8 b2_0 = *(const short8*)(fw + c * FSTRIDE + g * 8);
    short8 b2_1 = *(const short8*)(fw + c * FSTRIDE + 32 + g * 8);
    // ---- GEMM2: f1^T = W1^T f0^T  (M=64, K=64); A2 frags from L1 ----
#pragma unroll
    for (int mt = 0; mt < 4; ++mt) {
      f32x4 acc = {0.f, 0.f, 0.f, 0.f};
      acc = __builtin_amdgcn_mfma_f32_16x16x32_bf16(
          *(const short8*)(wsA + A2_SH + ((mt * 2 + 0) * 64 + l) * 8), b2_0, acc, 0, 0, 0);
      acc = __builtin_amdgcn_mfma_f32_16x16x32_bf16(
          *(const short8*)(wsA + A2_SH + ((mt * 2 + 1) * 64 + l) * 8), b2_1, acc, 0, 0, 0);
      float4 bv = *(const float4*)(b1 + mt * 16 + g * 4);  // L1 hit
      uint2 pp;
      pp.x = pack2(fmaxf(acc[0] + bv.x, 0.f), fmaxf(acc[1] + bv.y, 0.f));
      pp.y = pack2(fmaxf(acc[2] + bv.z, 0.f), fmaxf(acc[3] + bv.w, 0.f));
      *(uint2*)(fw + c * FSTRIDE + mt * 16 + g * 4) = pp;   // f1 overwrites f0
    }
    short8 b3_0 = *(const short8*)(fw + c * FSTRIDE + g * 8);
    short8 b3_1 = *(const short8*)(fw + c * FSTRIDE + 32 + g * 8);

    // ---- heads: runtime n-loop; A3/w2v from L2 (wave reads 1KB contiguous);
    //      output staged in wave-private LDS then stored as full 64B lines ----
#pragma unroll 2
    for (int n = 0; n < 32; ++n) {
      short8 a30 = *(const short8*)(wsA + A3_SH + ((n * 2 + 0) * 64 + l) * 8);
      short8 a31 = *(const short8*)(wsA + A3_SH + ((n * 2 + 1) * 64 + l) * 8);
      float4 wl  = *(const float4*)(w2v + n * 256 + l * 4);
      float4 hbv = *(const float4*)(hb1 + n * 16 + g * 4);
      f32x4 acc = {0.f, 0.f, 0.f, 0.f};
      acc = __builtin_amdgcn_mfma_f32_16x16x32_bf16(a30, b3_0, acc, 0, 0, 0);
      acc = __builtin_amdgcn_mfma_f32_16x16x32_bf16(a31, b3_1, acc, 0, 0, 0);
      float s = fmaxf(acc[0] + hbv.x, 0.f) * wl.x
              + fmaxf(acc[1] + hbv.y, 0.f) * wl.y
              + fmaxf(acc[2] + hbv.z, 0.f) * wl.z
              + fmaxf(acc[3] + hbv.w, 0.f) * wl.w;
      s += __shfl_xor(s, 16);
      s += __shfl_xor(s, 32);
      s += hb2[n];
      if (g == (n >> 3)) ow[c * OSTRIDE + n] = s;  // conflict-free (stride 33)
    }
    // wave-private readback (<=2-way bank alias = free) + full-line stores
    float r[8];
#pragma unroll
    for (int j = 0; j < 8; ++j) r[j] = ow[c * OSTRIDE + g * 8 + j];
    float4 v0 = {r[0], r[1], r[2], r[3]};
    float4 v1 = {r[4], r[5], r[6], r[7]};
    float* op = out + (size_t)(rowbase + t * 16 + c) * 32 + g * 8;
    *(float4*)op = v0;
    *(float4*)(op + 4) = v1;
  }
}

extern "C" void kernel_launch(void* const* d_in, const int* in_sizes, int n_in,
                              void* d_out, int out_size, void* d_ws, size_t ws_size,
                              hipStream_t stream) {
  const float* x   = (const float*)d_in[0];
  const float* W0  = (const float*)d_in[1];
  const float* b0  = (const float*)d_in[2];
  const float* W1  = (const float*)d_in[3];
  const float* b1  = (const float*)d_in[4];
  const float* hw1 = (const float*)d_in[5];
  const float* hb1 = (const float*)d_in[6];
  const float* hw2 = (const float*)d_in[7];
  const float* hb2 = (const float*)d_in[8];
  float* out = (float*)d_out;

  short* wsA = (short*)d_ws;
  float* w2v = (float*)((char*)d_ws + W2V_OFF);

  prep_kernel<<<128, 256, 0, stream>>>(W0, W1, hw1, hw2, wsA, w2v);
  mhc_kernel<<<NUM_WG, WG_THREADS, 0, stream>>>(x, b0, b1, hb1, hb2, wsA, w2v, out);
}

// Round 11
// 138.218 us; speedup vs baseline: 1.2541x; 1.1534x over previous
//
#include <hip/hip_runtime.h>
#include <stdint.h>

typedef __attribute__((ext_vector_type(8))) short short8;
typedef __attribute__((ext_vector_type(4))) float f32x4;

// ---------------- geometry ----------------
#define B_TOTAL     131072
#define WG_THREADS  512
#define WAVES       8
// 4 tiles per wave, processed as 2 pairs of 2 (ILP in head loop)
#define ROWS_PER_WG (WAVES * 4 * 16)        // 512
#define NUM_WG      (B_TOTAL / ROWS_PER_WG) // 256 -> 1 WG/CU

// ---------------- d_ws layout (shorts) ----------------
// A1: W0^T frags  [mt4][kt4][64][8] bf16 = 16 KB @ 0     (L1-resident)
// A2: W1^T frags  [mt4][kt2][64][8] bf16 =  8 KB @ 8192  (L1-resident)
// A3: hw1^T frags [n32][kt2][64][8] bf16 = 64 KB @ 12288 (LDS-staged per WG)
#define A1_SH   0
#define A2_SH   8192
#define A3_SH   12288

// LDS: a3s 64 KB (WG-shared) + fw 18 KB (wave-private) + obuf 33 KB (wave-private)
//      = 115 KB -> 1 WG/CU
#define FSTRIDE 72
#define OSTRIDE 33

__device__ __forceinline__ short f2bf(float x) {
  union { float f; uint32_t u; } v; v.f = x;
  uint32_t r = (v.u + 0x7FFFu + ((v.u >> 16) & 1u)) >> 16;
  return (short)r;
}

__device__ __forceinline__ uint32_t pack2(float a, float b) {
  return (uint32_t)(uint16_t)f2bf(a) | ((uint32_t)(uint16_t)f2bf(b) << 16);
}

// ---------------- weight prep: f32 -> bf16 MFMA A-fragment order ----------------
__global__ void prep_kernel(const float* __restrict__ W0, const float* __restrict__ W1,
                            const float* __restrict__ hw1, short* __restrict__ wsA) {
  int idx = blockIdx.x * 256 + threadIdx.x;
  int stride = gridDim.x * 256;
  // A1[m][k] = W0[k][m]  (m: hidden 64, k: input 128)
  for (int i = idx; i < 8192; i += stride) {
    int j = i & 7, l = (i >> 3) & 63, kt = (i >> 9) & 3, mt = i >> 11;
    int m = mt * 16 + (l & 15), k = kt * 32 + (l >> 4) * 8 + j;
    wsA[A1_SH + i] = f2bf(W0[k * 64 + m]);
  }
  // A2[m][k] = W1[k][m]
  for (int i = idx; i < 4096; i += stride) {
    int j = i & 7, l = (i >> 3) & 63, kt = (i >> 9) & 1, mt = i >> 10;
    int m = mt * 16 + (l & 15), k = kt * 32 + (l >> 4) * 8 + j;
    wsA[A2_SH + i] = f2bf(W1[k * 64 + m]);
  }
  // A3[n*16+d][k] = hw1[n][k][d]
  for (int i = idx; i < 32768; i += stride) {
    int j = i & 7, l = (i >> 3) & 63, kt = (i >> 9) & 1, n = i >> 10;
    int d = l & 15, k = kt * 32 + (l >> 4) * 8 + j;
    wsA[A3_SH + i] = f2bf(hw1[(n * 64 + k) * 16 + d]);
  }
}

// ---------------- fused main kernel ----------------
// 1 WG/CU (115 KB LDS). Head-phase A3 comes from LDS (staged once, shared by
// all 8 waves x 4 tiles) instead of per-wave L2 streams (R10: 768 MB of L2
// re-reads was the bottleneck). 2-tile pairs give 2 independent MFMA chains.
__global__ __launch_bounds__(WG_THREADS, 4)
void mhc_kernel(const float* __restrict__ x, const float* __restrict__ b0,
                const float* __restrict__ b1, const float* __restrict__ hb1,
                const float* __restrict__ hb2, const float* __restrict__ hw2,
                const short* __restrict__ wsA, float* __restrict__ out) {
  __shared__ short a3s[32768];                    // 64 KB, WG-shared
  __shared__ short fwbuf[WAVES * 16 * FSTRIDE];   // 18 KB, wave-private
  __shared__ float obuf[WAVES * 2 * 16 * OSTRIDE];// 33 KB, wave-private (2 tiles)

  const int tid = threadIdx.x;
  const int w = tid >> 6, l = tid & 63;
  const int g = l >> 4, c = l & 15;
  const int rowbase = blockIdx.x * ROWS_PER_WG + w * 64;

  // ---- stage A3 into LDS (64 KB linear copy, coalesced both sides) ----
  {
    const uint4* src = (const uint4*)(wsA + A3_SH);  // 4096 uint4
    uint4* dst = (uint4*)a3s;
    for (int i = tid; i < 4096; i += WG_THREADS) dst[i] = src[i];
  }
  __syncthreads();

  short* fw = fwbuf + w * (16 * FSTRIDE);
  float* ow = obuf + w * (2 * 16 * OSTRIDE);

  for (int tp = 0; tp < 2; ++tp) {
    const int trow = rowbase + tp * 32;

    // ---- issue BOTH tiles' x loads up front (tile1 latency hides under
    //      tile0 backbone) ----
    float4 xr[2][4][2];
#pragma unroll
    for (int tt = 0; tt < 2; ++tt) {
      const float* xp = x + (size_t)(trow + tt * 16 + c) * 128 + g * 8;
#pragma unroll
      for (int kt = 0; kt < 4; ++kt) {
        xr[tt][kt][0] = *(const float4*)(xp + kt * 32);
        xr[tt][kt][1] = *(const float4*)(xp + kt * 32 + 4);
      }
    }

    short8 b3[2][2];
#pragma unroll
    for (int tt = 0; tt < 2; ++tt) {
      short8 bx[4];
#pragma unroll
      for (int kt = 0; kt < 4; ++kt) {
        float4 a = xr[tt][kt][0], bq = xr[tt][kt][1];
        short8 v;
        v[0] = f2bf(a.x);  v[1] = f2bf(a.y);  v[2] = f2bf(a.z);  v[3] = f2bf(a.w);
        v[4] = f2bf(bq.x); v[5] = f2bf(bq.y); v[6] = f2bf(bq.z); v[7] = f2bf(bq.w);
        bx[kt] = v;
      }
      // GEMM1: f0^T = W0^T x^T (M=64,K=128); A1 frags from L1
#pragma unroll
      for (int mt = 0; mt < 4; ++mt) {
        f32x4 acc = {0.f, 0.f, 0.f, 0.f};
#pragma unroll
        for (int kt = 0; kt < 4; ++kt)
          acc = __builtin_amdgcn_mfma_f32_16x16x32_bf16(
              *(const short8*)(wsA + A1_SH + ((mt * 4 + kt) * 64 + l) * 8),
              bx[kt], acc, 0, 0, 0);
        float4 bv = *(const float4*)(b0 + mt * 16 + g * 4);
        uint2 pp;
        pp.x = pack2(fmaxf(acc[0] + bv.x, 0.f), fmaxf(acc[1] + bv.y, 0.f));
        pp.y = pack2(fmaxf(acc[2] + bv.z, 0.f), fmaxf(acc[3] + bv.w, 0.f));
        *(uint2*)(fw + c * FSTRIDE + mt * 16 + g * 4) = pp;
      }
      short8 b2_0 = *(const short8*)(fw + c * FSTRIDE + g * 8);
      short8 b2_1 = *(const short8*)(fw + c * FSTRIDE + 32 + g * 8);
      // GEMM2: f1^T = W1^T f0^T (M=64,K=64); A2 frags from L1
#pragma unroll
      for (int mt = 0; mt < 4; ++mt) {
        f32x4 acc = {0.f, 0.f, 0.f, 0.f};
        acc = __builtin_amdgcn_mfma_f32_16x16x32_bf16(
            *(const short8*)(wsA + A2_SH + ((mt * 2 + 0) * 64 + l) * 8), b2_0, acc, 0, 0, 0);
        acc = __builtin_amdgcn_mfma_f32_16x16x32_bf16(
            *(const short8*)(wsA + A2_SH + ((mt * 2 + 1) * 64 + l) * 8), b2_1, acc, 0, 0, 0);
        float4 bv = *(const float4*)(b1 + mt * 16 + g * 4);
        uint2 pp;
        pp.x = pack2(fmaxf(acc[0] + bv.x, 0.f), fmaxf(acc[1] + bv.y, 0.f));
        pp.y = pack2(fmaxf(acc[2] + bv.z, 0.f), fmaxf(acc[3] + bv.w, 0.f));
        *(uint2*)(fw + c * FSTRIDE + mt * 16 + g * 4) = pp;
      }
      b3[tt][0] = *(const short8*)(fw + c * FSTRIDE + g * 8);
      b3[tt][1] = *(const short8*)(fw + c * FSTRIDE + 32 + g * 8);
    }

    // ---- heads: A3 from LDS; 2 independent acc chains (tile pair) per n ----
#pragma unroll 2
    for (int n = 0; n < 32; ++n) {
      short8 a30 = *(const short8*)(a3s + (n * 2 + 0) * 512 + l * 8);
      short8 a31 = *(const short8*)(a3s + (n * 2 + 1) * 512 + l * 8);
      float4 wl  = *(const float4*)(hw2 + n * 16 + g * 4);  // L1 (2 KB total)
      float4 hbv = *(const float4*)(hb1 + n * 16 + g * 4);  // L1
      float hb2n = hb2[n];
      f32x4 acc0 = {0.f, 0.f, 0.f, 0.f};
      f32x4 acc1 = {0.f, 0.f, 0.f, 0.f};
      acc0 = __builtin_amdgcn_mfma_f32_16x16x32_bf16(a30, b3[0][0], acc0, 0, 0, 0);
      acc1 = __builtin_amdgcn_mfma_f32_16x16x32_bf16(a30, b3[1][0], acc1, 0, 0, 0);
      acc0 = __builtin_amdgcn_mfma_f32_16x16x32_bf16(a31, b3[0][1], acc0, 0, 0, 0);
      acc1 = __builtin_amdgcn_mfma_f32_16x16x32_bf16(a31, b3[1][1], acc1, 0, 0, 0);
      float s0 = fmaxf(acc0[0] + hbv.x, 0.f) * wl.x
               + fmaxf(acc0[1] + hbv.y, 0.f) * wl.y
               + fmaxf(acc0[2] + hbv.z, 0.f) * wl.z
               + fmaxf(acc0[3] + hbv.w, 0.f) * wl.w;
      float s1 = fmaxf(acc1[0] + hbv.x, 0.f) * wl.x
               + fmaxf(acc1[1] + hbv.y, 0.f) * wl.y
               + fmaxf(acc1[2] + hbv.z, 0.f) * wl.z
               + fmaxf(acc1[3] + hbv.w, 0.f) * wl.w;
      s0 += __shfl_xor(s0, 16);  s1 += __shfl_xor(s1, 16);
      s0 += __shfl_xor(s0, 32);  s1 += __shfl_xor(s1, 32);
      s0 += hb2n;                s1 += hb2n;
      if (g == (n >> 3)) {
        ow[c * OSTRIDE + n] = s0;                      // conflict-free (stride 33)
        ow[16 * OSTRIDE + c * OSTRIDE + n] = s1;
      }
    }

    // ---- coalesced stores: full 64B lines per row ----
#pragma unroll
    for (int tt = 0; tt < 2; ++tt) {
      float r[8];
#pragma unroll
      for (int j = 0; j < 8; ++j) r[j] = ow[tt * 16 * OSTRIDE + c * OSTRIDE + g * 8 + j];
      float4 v0 = {r[0], r[1], r[2], r[3]};
      float4 v1 = {r[4], r[5], r[6], r[7]};
      float* op = out + (size_t)(trow + tt * 16 + c) * 32 + g * 8;
      *(float4*)op = v0;
      *(float4*)(op + 4) = v1;
    }
  }
}

extern "C" void kernel_launch(void* const* d_in, const int* in_sizes, int n_in,
                              void* d_out, int out_size, void* d_ws, size_t ws_size,
                              hipStream_t stream) {
  const float* x   = (const float*)d_in[0];
  const float* W0  = (const float*)d_in[1];
  const float* b0  = (const float*)d_in[2];
  const float* W1  = (const float*)d_in[3];
  const float* b1  = (const float*)d_in[4];
  const float* hw1 = (const float*)d_in[5];
  const float* hb1 = (const float*)d_in[6];
  const float* hw2 = (const float*)d_in[7];
  const float* hb2 = (const float*)d_in[8];
  float* out = (float*)d_out;

  short* wsA = (short*)d_ws;

  prep_kernel<<<128, 256, 0, stream>>>(W0, W1, hw1, wsA);
  mhc_kernel<<<NUM_WG, WG_THREADS, 0, stream>>>(x, b0, b1, hb1, hb2, hw2, wsA, out);
}